// Round 8
// baseline (59.771 us; speedup 1.0000x reference)
//
#include <hip/hip_runtime.h>

#define NB 8
#define SS 2048
#define DD 128
// 1/sqrt(8) * log2(e): exp(x/sqrt8) = exp2(x*SCALE2)
#define SCALE2 0.5101817664764817f
#define NEGINF -3.0e38f

typedef _Float16 f16x8 __attribute__((ext_vector_type(8)));
typedef float f32x16 __attribute__((ext_vector_type(16)));
typedef unsigned short u16;
typedef u16 u16x8 __attribute__((ext_vector_type(8)));
typedef unsigned int u32;

__device__ __forceinline__ u32 pkrtz(float a, float b) {
    u32 w;
    asm("v_cvt_pkrtz_f16_f32 %0, %1, %2" : "=v"(w) : "v"(a), "v"(b));
    return w;
}

// async global->LDS, 16B/lane; LDS dest is wave-uniform base (HW adds lane*16)
__device__ __forceinline__ void gload_lds16(const u16* g, u16* l) {
    __builtin_amdgcn_global_load_lds(
        (const __attribute__((address_space(1))) unsigned*)g,
        (__attribute__((address_space(3))) unsigned*)l, 16, 0, 0);
}

// ---------------- Kernel 1: U = quantum_measure(x, theta) ----------------
// Fragment-order f16 layouts (per batch, per 32-row s-tile t), for 32x32x16 MFMA:
//  G1 : chunk16B[t*512 + kc*64 + hi*32 + r]  holds U[t*32+r][kc*16+hi*8 + 0..7]
//  G2t: chunk16B[t*512 + (dt*2+kc2)*64 + hi*32 + lo5] holds U[t*32+kc2*16+hi*8+u][dt*32+lo5]
__global__ __launch_bounds__(512) void qmeasure_kernel(const float* __restrict__ x,
                                                       const float* __restrict__ theta,
                                                       u16* __restrict__ G1,
                                                       u16* __restrict__ G2) {
    __shared__ u16 olds[32][136];
    const int bid = blockIdx.x;
    const int b = bid & 7;
    const int t = bid >> 3;
    const int tid = threadIdx.x;
    const int s = tid >> 4;
    const int c = tid & 15;

    float th[8];
    *(float4*)th = *(const float4*)theta;
    *(float4*)(th + 4) = *(const float4*)(theta + 4);

    const float* xp = x + (((size_t)b * SS + t * 32 + s) * DD) + c * 8;
    float4 a = *(const float4*)xp;
    float4 a2 = *(const float4*)(xp + 4);
    float cc[8];
    cc[0] = __cosf(a.x + th[0]);  cc[1] = __cosf(a.y + th[1]);
    cc[2] = __cosf(a.z + th[2]);  cc[3] = __cosf(a.w + th[3]);
    cc[4] = __cosf(a2.x + th[4]); cc[5] = __cosf(a2.y + th[5]);
    cc[6] = __cosf(a2.z + th[6]); cc[7] = __cosf(a2.w + th[7]);
    float o[8];
    o[1] = cc[0] * cc[1];
    o[2] = o[1] * cc[2]; o[3] = o[2] * cc[3]; o[4] = o[3] * cc[4];
    o[5] = o[4] * cc[5]; o[6] = o[5] * cc[6]; o[7] = o[6] * cc[7];
    float z = cc[1] * cc[2]; z *= cc[3]; z *= cc[4]; z *= cc[5]; z *= cc[6]; z *= cc[7];
    o[0] = z;

    u16x8 w;
#pragma unroll
    for (int e = 0; e < 8; ++e) w[e] = __builtin_bit_cast(u16, (_Float16)o[e]);
    *(u16x8*)&olds[s][c * 8] = w;
    __syncthreads();

    {
        const int kc = tid >> 6, hh = (tid >> 5) & 1, r = tid & 31;
        u16x8 g;
#pragma unroll
        for (int u = 0; u < 8; ++u) g[u] = olds[r][kc * 16 + hh * 8 + u];
        *(u16x8*)(G1 + (size_t)b * (SS * DD) + ((size_t)t * 512 + tid) * 8) = g;
    }
    {
        const int lo5 = tid & 31;
        const int hh = (tid >> 5) & 1;
        const int dkc = tid >> 6;
        const int dt = dkc >> 1, kc2 = dkc & 1;
        u16x8 g;
#pragma unroll
        for (int u = 0; u < 8; ++u) g[u] = olds[kc2 * 16 + hh * 8 + u][dt * 32 + lo5];
        const int chunk = t * 512 + dkc * 64 + hh * 32 + lo5;
        *(u16x8*)(G2 + (size_t)b * (SS * DD) + (size_t)chunk * 8) = g;
    }
}

// ---------------- Kernel 2: flash attention, latency-hidden, barrier-free ----------------
// grid 256 = 8 batches (bid&7) x 32 q-groups of 64 rows. 512 thr = 8 waves = 2qw x 4kq.
// Zero barriers in main loop. V(t+1) prefetched into a WAVE-PRIVATE LDS slot via
// global_load_lds (no vf register buffer, no cross-wave hazard); K(t+1) prefetched into
// the alternate register buffer (kfA/kfB, statically named). Both latencies hide under a
// full iteration of compute. Manual vmcnt(16) before PV = exactly the 16 loads issued
// this iter (8 V-gloads + 8 K-loads), so V(t)'s DMA is drained (rule #18/#21).
template <bool LAST>
__device__ __forceinline__ void attn_step(const f16x8* __restrict__ kf,
                                          const u16* __restrict__ vlds, int lane8,
                                          const f16x8* __restrict__ qf,
                                          f32x16* __restrict__ accT,
                                          float& m, float& l) {
    // S^T = K . Q^T, two independent 4-chains
    f32x16 acA, acB;
#pragma unroll
    for (int e = 0; e < 16; ++e) { acA[e] = 0.f; acB[e] = 0.f; }
    __builtin_amdgcn_s_setprio(1);
#pragma unroll
    for (int kc = 0; kc < 4; ++kc)
        acA = __builtin_amdgcn_mfma_f32_32x32x16_f16(kf[kc], qf[kc], acA, 0, 0, 0);
#pragma unroll
    for (int kc = 4; kc < 8; ++kc)
        acB = __builtin_amdgcn_mfma_f32_32x32x16_f16(kf[kc], qf[kc], acB, 0, 0, 0);
    __builtin_amdgcn_s_setprio(0);
    f32x16 acc = acA + acB;

    // online softmax (exp2 domain), defer-max THR=8
    float ma = fmaxf(fmaxf(acc[0], acc[1]), acc[2]);
    float mb = fmaxf(fmaxf(acc[8], acc[9]), acc[10]);
    ma = fmaxf(fmaxf(ma, acc[3]), acc[4]);
    mb = fmaxf(fmaxf(mb, acc[11]), acc[12]);
    ma = fmaxf(fmaxf(ma, acc[5]), acc[6]);
    mb = fmaxf(fmaxf(mb, acc[13]), acc[14]);
    ma = fmaxf(fmaxf(ma, acc[7]), mb);
    float tmax = fmaxf(ma, acc[15]) * SCALE2;
    tmax = fmaxf(tmax, __shfl_xor(tmax, 32));
    if (!__all(tmax <= m + 8.f)) {
        const float mnew = fmaxf(m, tmax);
        const float corr = exp2f(m - mnew);
        l *= corr;
#pragma unroll
        for (int dt = 0; dt < 4; ++dt)
#pragma unroll
            for (int e = 0; e < 16; ++e) accT[dt][e] *= corr;
        m = mnew;
    }
#pragma unroll
    for (int r = 0; r < 16; ++r) acc[r] = exp2f(acc[r] * SCALE2 - m);
    float s0 = (acc[0] + acc[1]) + (acc[2] + acc[3]);
    float s1 = (acc[4] + acc[5]) + (acc[6] + acc[7]);
    float s2 = (acc[8] + acc[9]) + (acc[10] + acc[11]);
    float s3 = (acc[12] + acc[13]) + (acc[14] + acc[15]);
    float rowsum = (s0 + s1) + (s2 + s3);
    rowsum += __shfl_xor(rowsum, 32);
    l += rowsum;

    // P^T B-frags via cvt_pk + permlane32_swap
    f16x8 pa[2];
#pragma unroll
    for (int kc2 = 0; kc2 < 2; ++kc2) {
        const int r0 = kc2 * 8;
        u32 w0 = pkrtz(acc[r0 + 0], acc[r0 + 1]);
        u32 w2 = pkrtz(acc[r0 + 4], acc[r0 + 5]);
        asm("v_permlane32_swap_b32 %0, %1" : "+v"(w0), "+v"(w2));
        u32 w1 = pkrtz(acc[r0 + 2], acc[r0 + 3]);
        u32 w3 = pkrtz(acc[r0 + 6], acc[r0 + 7]);
        asm("v_permlane32_swap_b32 %0, %1" : "+v"(w1), "+v"(w3));
        union { u32 w[4]; f16x8 v; } u;
        u.w[0] = w0; u.w[1] = w1; u.w[2] = w2; u.w[3] = w3;
        pa[kc2] = u.v;
    }

    // V(t)'s global_load_lds DMA is complete once <=16 newer loads remain
    if (LAST) asm volatile("s_waitcnt vmcnt(0)" ::: "memory");
    else      asm volatile("s_waitcnt vmcnt(16)" ::: "memory");
    __builtin_amdgcn_sched_barrier(0);

    // O^T += V^T . P^T, V frags read JIT from wave-private LDS (ds_read_b128)
    __builtin_amdgcn_s_setprio(1);
#pragma unroll
    for (int dt = 0; dt < 4; ++dt) {
        f16x8 vf0 = *(const f16x8*)(vlds + (dt * 2 + 0) * 512 + lane8);
        f16x8 vf1 = *(const f16x8*)(vlds + (dt * 2 + 1) * 512 + lane8);
        f32x16 a = accT[dt];
        a = __builtin_amdgcn_mfma_f32_32x32x16_f16(vf0, pa[0], a, 0, 0, 0);
        a = __builtin_amdgcn_mfma_f32_32x32x16_f16(vf1, pa[1], a, 0, 0, 0);
        accT[dt] = a;
    }
    __builtin_amdgcn_s_setprio(0);
}

__global__ __launch_bounds__(512, 2) void qattn_kernel(const u16* __restrict__ G1g,
                                                       const u16* __restrict__ G2g,
                                                       float* __restrict__ out) {
    __shared__ __align__(16) u16 vbuf[2][8][4096];   // wave-private V dbuf, 128 KB

    const int tid = threadIdx.x;
    const int lane = tid & 63;
    const int wave = tid >> 6;
    const int lo5 = lane & 31;
    const int hi = lane >> 5;
    const int qw = wave & 1;
    const int kq = wave >> 1;
    const int bid = blockIdx.x;
    const int b = bid & 7;
    const int qg = bid >> 3;
    const int lane8 = lane * 8;

    const u16* G1b = G1g + (size_t)b * (SS * DD);
    const u16* G2b = G2g + (size_t)b * (SS * DD);

    // Q fragments (B-operand)
    f16x8 qf[8];
    {
        const u16* qp = G1b + (size_t)(qg * 2 + qw) * 4096 + lane8;
#pragma unroll
        for (int kc = 0; kc < 8; ++kc) qf[kc] = *(const f16x8*)(qp + kc * 512);
    }

    f32x16 accT[4];
#pragma unroll
    for (int dt = 0; dt < 4; ++dt)
#pragma unroll
        for (int e = 0; e < 16; ++e) accT[dt][e] = 0.f;
    float m = NEGINF, l = 0.f;

    u16* const myv0 = &vbuf[0][wave][0];
    u16* const myv1 = &vbuf[1][wave][0];

    // prologue: V(kq*16) -> myv0 (DMA), K(kq*16) -> kfA (regs)
    {
        const u16* vsrc = G2b + (size_t)(kq * 16) * 4096 + lane8;
        __builtin_amdgcn_sched_barrier(0);
#pragma unroll
        for (int w = 0; w < 8; ++w) gload_lds16(vsrc + w * 512, myv0 + w * 512);
        __builtin_amdgcn_sched_barrier(0);
    }
    f16x8 kfA[8], kfB[8];
    {
        const u16* kp = G1b + (size_t)(kq * 16) * 4096 + lane8;
#pragma unroll
        for (int j = 0; j < 8; ++j) kfA[j] = *(const f16x8*)(kp + j * 512);
    }

    for (int it2 = 0; it2 < 8; ++it2) {
        const int t = kq * 16 + it2 * 2;
        // even tile t: stage V(t+1)->myv1, K(t+1)->kfB; compute with kfA/myv0
        {
            const u16* vsrc = G2b + (size_t)(t + 1) * 4096 + lane8;
            __builtin_amdgcn_sched_barrier(0);
#pragma unroll
            for (int w = 0; w < 8; ++w) gload_lds16(vsrc + w * 512, myv1 + w * 512);
            __builtin_amdgcn_sched_barrier(0);
            const u16* np = G1b + (size_t)(t + 1) * 4096 + lane8;
#pragma unroll
            for (int j = 0; j < 8; ++j) kfB[j] = *(const f16x8*)(np + j * 512);
            attn_step<false>(kfA, myv0, lane8, qf, accT, m, l);
        }
        // odd tile t+1: stage V(t+2)->myv0, K(t+2)->kfA; compute with kfB/myv1
        if (it2 < 7) {
            const u16* vsrc = G2b + (size_t)(t + 2) * 4096 + lane8;
            __builtin_amdgcn_sched_barrier(0);
#pragma unroll
            for (int w = 0; w < 8; ++w) gload_lds16(vsrc + w * 512, myv0 + w * 512);
            __builtin_amdgcn_sched_barrier(0);
            const u16* np = G1b + (size_t)(t + 2) * 4096 + lane8;
#pragma unroll
            for (int j = 0; j < 8; ++j) kfA[j] = *(const f16x8*)(np + j * 512);
            attn_step<false>(kfB, myv1, lane8, qf, accT, m, l);
        } else {
            attn_step<true>(kfB, myv1, lane8, qf, accT, m, l);
        }
    }

    // ---- 4-way kq merge via LDS (alias dead staging buffers) ----
    __syncthreads();
    float* obuf = (float*)(&vbuf[0][0][0]);                           // [2][3][2][16][64] f32
    float* mlb = (float*)((unsigned char*)(&vbuf[0][0][0]) + 49152);  // [2][3][2][32] f32
    float* orow = out + ((size_t)b * SS + qg * 64 + qw * 32 + lo5) * DD;
#pragma unroll
    for (int half = 0; half < 2; ++half) {
        if (kq > 0) {
            if (half == 0 && hi == 0) {
                mlb[((qw * 3 + (kq - 1)) * 2 + 0) * 32 + lo5] = m;
                mlb[((qw * 3 + (kq - 1)) * 2 + 1) * 32 + lo5] = l;
            }
#pragma unroll
            for (int dh = 0; dh < 2; ++dh)
#pragma unroll
                for (int r = 0; r < 16; ++r)
                    obuf[(((qw * 3 + (kq - 1)) * 2 + dh) * 16 + r) * 64 + lane] =
                        accT[half * 2 + dh][r];
        }
        __syncthreads();
        if (kq == 0) {
            const float mj0 = mlb[((qw * 3 + 0) * 2 + 0) * 32 + lo5];
            const float lj0 = mlb[((qw * 3 + 0) * 2 + 1) * 32 + lo5];
            const float mj1 = mlb[((qw * 3 + 1) * 2 + 0) * 32 + lo5];
            const float lj1 = mlb[((qw * 3 + 1) * 2 + 1) * 32 + lo5];
            const float mj2 = mlb[((qw * 3 + 2) * 2 + 0) * 32 + lo5];
            const float lj2 = mlb[((qw * 3 + 2) * 2 + 1) * 32 + lo5];
            const float ms = fmaxf(fmaxf(m, mj0), fmaxf(mj1, mj2));
            const float w0 = exp2f(m - ms), w1 = exp2f(mj0 - ms);
            const float w2 = exp2f(mj1 - ms), w3 = exp2f(mj2 - ms);
            const float linv = 1.f / (l * w0 + lj0 * w1 + lj1 * w2 + lj2 * w3);
#pragma unroll
            for (int dh = 0; dh < 2; ++dh) {
                const int dt = half * 2 + dh;
#pragma unroll
                for (int r = 0; r < 16; ++r) {
                    const float o = accT[dt][r] * w0 +
                                    obuf[(((qw * 3 + 0) * 2 + dh) * 16 + r) * 64 + lane] * w1 +
                                    obuf[(((qw * 3 + 1) * 2 + dh) * 16 + r) * 64 + lane] * w2 +
                                    obuf[(((qw * 3 + 2) * 2 + dh) * 16 + r) * 64 + lane] * w3;
                    const int drow = (r & 3) + 8 * (r >> 2) + 4 * hi;
                    orow[dt * 32 + drow] = o * linv;
                }
            }
        }
        __syncthreads();
    }
}

extern "C" void kernel_launch(void* const* d_in, const int* in_sizes, int n_in,
                              void* d_out, int out_size, void* d_ws, size_t ws_size,
                              hipStream_t stream) {
    const float* x = (const float*)d_in[0];
    const float* theta = (const float*)d_in[1];
    float* outp = (float*)d_out;
    u16* G1 = (u16*)d_ws;                       // 4 MB
    u16* G2 = G1 + (size_t)NB * SS * DD;        // +4 MB

    qmeasure_kernel<<<512, 512, 0, stream>>>(x, theta, G1, G2);
    qattn_kernel<<<256, 512, 0, stream>>>(G1, G2, outp);
}

// Round 9
// 40.255 us; speedup vs baseline: 1.4848x; 1.4848x over previous
//
#include <hip/hip_runtime.h>

#define NB 8
#define SS 2048
#define DD 128
// 1/sqrt(8) * log2(e): exp(x/sqrt8) = exp2(x*SCALE2)
#define SCALE2 0.5101817664764817f
#define NEGINF -3.0e38f

typedef _Float16 f16x8 __attribute__((ext_vector_type(8)));
typedef float f32x16 __attribute__((ext_vector_type(16)));
typedef unsigned short u16;
typedef u16 u16x8 __attribute__((ext_vector_type(8)));
typedef unsigned int u32;

__device__ __forceinline__ u32 pkrtz(float a, float b) {
    u32 w;
    asm("v_cvt_pkrtz_f16_f32 %0, %1, %2" : "=v"(w) : "v"(a), "v"(b));
    return w;
}

// ---------------- Kernel 1: U = quantum_measure(x, theta) ----------------
// Fragment-order f16 layouts (per batch, per 32-row s-tile t), for 32x32x16 MFMA:
//  G1 : chunk16B[t*512 + kc*64 + hi*32 + r]  holds U[t*32+r][kc*16+hi*8 + 0..7]
//  G2t: chunk16B[t*512 + (dt*2+kc2)*64 + hi*32 + lo5] holds U[t*32+kc2*16+hi*8+u][dt*32+lo5]
__global__ __launch_bounds__(512) void qmeasure_kernel(const float* __restrict__ x,
                                                       const float* __restrict__ theta,
                                                       u16* __restrict__ G1,
                                                       u16* __restrict__ G2) {
    __shared__ u16 olds[32][136];
    const int bid = blockIdx.x;
    const int b = bid & 7;
    const int t = bid >> 3;
    const int tid = threadIdx.x;
    const int s = tid >> 4;
    const int c = tid & 15;

    float th[8];
    *(float4*)th = *(const float4*)theta;
    *(float4*)(th + 4) = *(const float4*)(theta + 4);

    const float* xp = x + (((size_t)b * SS + t * 32 + s) * DD) + c * 8;
    float4 a = *(const float4*)xp;
    float4 a2 = *(const float4*)(xp + 4);
    float cc[8];
    cc[0] = __cosf(a.x + th[0]);  cc[1] = __cosf(a.y + th[1]);
    cc[2] = __cosf(a.z + th[2]);  cc[3] = __cosf(a.w + th[3]);
    cc[4] = __cosf(a2.x + th[4]); cc[5] = __cosf(a2.y + th[5]);
    cc[6] = __cosf(a2.z + th[6]); cc[7] = __cosf(a2.w + th[7]);
    float o[8];
    o[1] = cc[0] * cc[1];
    o[2] = o[1] * cc[2]; o[3] = o[2] * cc[3]; o[4] = o[3] * cc[4];
    o[5] = o[4] * cc[5]; o[6] = o[5] * cc[6]; o[7] = o[6] * cc[7];
    float z = cc[1] * cc[2]; z *= cc[3]; z *= cc[4]; z *= cc[5]; z *= cc[6]; z *= cc[7];
    o[0] = z;

    u16x8 w;
#pragma unroll
    for (int e = 0; e < 8; ++e) w[e] = __builtin_bit_cast(u16, (_Float16)o[e]);
    *(u16x8*)&olds[s][c * 8] = w;
    __syncthreads();

    {
        const int kc = tid >> 6, hh = (tid >> 5) & 1, r = tid & 31;
        u16x8 g;
#pragma unroll
        for (int u = 0; u < 8; ++u) g[u] = olds[r][kc * 16 + hh * 8 + u];
        *(u16x8*)(G1 + (size_t)b * (SS * DD) + ((size_t)t * 512 + tid) * 8) = g;
    }
    {
        const int lo5 = tid & 31;
        const int hh = (tid >> 5) & 1;
        const int dkc = tid >> 6;
        const int dt = dkc >> 1, kc2 = dkc & 1;
        u16x8 g;
#pragma unroll
        for (int u = 0; u < 8; ++u) g[u] = olds[kc2 * 16 + hh * 8 + u][dt * 32 + lo5];
        const int chunk = t * 512 + dkc * 64 + hh * 32 + lo5;
        *(u16x8*)(G2 + (size_t)b * (SS * DD) + (size_t)chunk * 8) = g;
    }
}

// ---------------- Kernel 2: flash attention, 4 waves/SIMD, barrier-free loop ----------
// grid 512 = 8 batches (bid&7, XCD-pinned) x 64 q-tiles of 32 rows. block 256 thr =
// 4 waves, wave = one kv-quarter (512 kv, 16 iters x 32). Direct global->reg frag loads
// (JIT, no prefetch buffers), zero LDS/barriers in main loop. <=128 VGPR (enforced) ->
// 16 waves/CU (2 blocks/CU): latency hidden by TLP, the one lever that has worked.
__global__ __launch_bounds__(256, 4) void qattn_kernel(const u16* __restrict__ G1g,
                                                       const u16* __restrict__ G2g,
                                                       float* __restrict__ out) {
    __shared__ float obuf[3][4][16][64];   // 48 KB: partials of waves 1..3
    __shared__ float mlb[3][2][32];        // m/l of waves 1..3

    const int tid = threadIdx.x;
    const int lane = tid & 63;
    const int kq = tid >> 6;        // wave = kv quarter 0..3
    const int lo5 = lane & 31;
    const int hi = lane >> 5;
    const int bid = blockIdx.x;
    const int b = bid & 7;
    const int qt = bid >> 3;        // q-tile 0..63 (32 rows)
    const int lane8 = lane * 8;

    const u16* G1b = G1g + (size_t)b * (SS * DD);
    const u16* G2b = G2g + (size_t)b * (SS * DD);

    // Q fragments (B-operand), persistent (32 VGPR)
    f16x8 qf[8];
    {
        const u16* qp = G1b + (size_t)qt * 4096 + lane8;
#pragma unroll
        for (int kc = 0; kc < 8; ++kc) qf[kc] = *(const f16x8*)(qp + kc * 512);
    }

    f32x16 accT[4];
#pragma unroll
    for (int dt = 0; dt < 4; ++dt)
#pragma unroll
        for (int e = 0; e < 16; ++e) accT[dt][e] = 0.f;
    float m = NEGINF, l = 0.f;

    for (int it = 0; it < 16; ++it) {
        const int t = kq * 16 + it;
        const u16* kp = G1b + (size_t)t * 4096 + lane8;
        const u16* vp = G2b + (size_t)t * 4096 + lane8;

        // S^T = K . Q^T (frags loaded JIT; dependent MFMA chain)
        f32x16 acc;
#pragma unroll
        for (int e = 0; e < 16; ++e) acc[e] = 0.f;
        __builtin_amdgcn_s_setprio(1);
#pragma unroll
        for (int kc = 0; kc < 8; ++kc) {
            f16x8 kf = *(const f16x8*)(kp + kc * 512);
            acc = __builtin_amdgcn_mfma_f32_32x32x16_f16(kf, qf[kc], acc, 0, 0, 0);
        }
        __builtin_amdgcn_s_setprio(0);

        // online softmax (exp2 domain), defer-max THR=8; lane ^32 shares q
        float ma = fmaxf(fmaxf(acc[0], acc[1]), acc[2]);
        float mb = fmaxf(fmaxf(acc[8], acc[9]), acc[10]);
        ma = fmaxf(fmaxf(ma, acc[3]), acc[4]);
        mb = fmaxf(fmaxf(mb, acc[11]), acc[12]);
        ma = fmaxf(fmaxf(ma, acc[5]), acc[6]);
        mb = fmaxf(fmaxf(mb, acc[13]), acc[14]);
        ma = fmaxf(fmaxf(ma, acc[7]), mb);
        float tmax = fmaxf(ma, acc[15]) * SCALE2;
        tmax = fmaxf(tmax, __shfl_xor(tmax, 32));
        if (!__all(tmax <= m + 8.f)) {
            const float mnew = fmaxf(m, tmax);
            const float corr = exp2f(m - mnew);
            l *= corr;
#pragma unroll
            for (int dt = 0; dt < 4; ++dt)
#pragma unroll
                for (int e = 0; e < 16; ++e) accT[dt][e] *= corr;
            m = mnew;
        }
#pragma unroll
        for (int r = 0; r < 16; ++r) acc[r] = exp2f(acc[r] * SCALE2 - m);
        float s0 = (acc[0] + acc[1]) + (acc[2] + acc[3]);
        float s1 = (acc[4] + acc[5]) + (acc[6] + acc[7]);
        float s2 = (acc[8] + acc[9]) + (acc[10] + acc[11]);
        float s3 = (acc[12] + acc[13]) + (acc[14] + acc[15]);
        float rowsum = (s0 + s1) + (s2 + s3);
        rowsum += __shfl_xor(rowsum, 32);
        l += rowsum;

        // P^T B-frags via cvt_pk + permlane32_swap
        f16x8 pa[2];
#pragma unroll
        for (int kc2 = 0; kc2 < 2; ++kc2) {
            const int r0 = kc2 * 8;
            u32 w0 = pkrtz(acc[r0 + 0], acc[r0 + 1]);
            u32 w2 = pkrtz(acc[r0 + 4], acc[r0 + 5]);
            asm("v_permlane32_swap_b32 %0, %1" : "+v"(w0), "+v"(w2));
            u32 w1 = pkrtz(acc[r0 + 2], acc[r0 + 3]);
            u32 w3 = pkrtz(acc[r0 + 6], acc[r0 + 7]);
            asm("v_permlane32_swap_b32 %0, %1" : "+v"(w1), "+v"(w3));
            union { u32 w[4]; f16x8 v; } u;
            u.w[0] = w0; u.w[1] = w1; u.w[2] = w2; u.w[3] = w3;
            pa[kc2] = u.v;
        }

        // O^T += V^T . P^T (V frags JIT, 2 per dt)
        __builtin_amdgcn_s_setprio(1);
#pragma unroll
        for (int dt = 0; dt < 4; ++dt) {
            f16x8 vf0 = *(const f16x8*)(vp + (dt * 2 + 0) * 512);
            f16x8 vf1 = *(const f16x8*)(vp + (dt * 2 + 1) * 512);
            f32x16 a = accT[dt];
            a = __builtin_amdgcn_mfma_f32_32x32x16_f16(vf0, pa[0], a, 0, 0, 0);
            a = __builtin_amdgcn_mfma_f32_32x32x16_f16(vf1, pa[1], a, 0, 0, 0);
            accT[dt] = a;
        }
        __builtin_amdgcn_s_setprio(0);
    }

    // ---- 4-way kq merge via LDS (single round) ----
    if (kq > 0) {
        if (hi == 0) {
            mlb[kq - 1][0][lo5] = m;
            mlb[kq - 1][1][lo5] = l;
        }
#pragma unroll
        for (int dt = 0; dt < 4; ++dt)
#pragma unroll
            for (int r = 0; r < 16; ++r)
                obuf[kq - 1][dt][r][lane] = accT[dt][r];
    }
    __syncthreads();
    if (kq == 0) {
        const float mj0 = mlb[0][0][lo5], lj0 = mlb[0][1][lo5];
        const float mj1 = mlb[1][0][lo5], lj1 = mlb[1][1][lo5];
        const float mj2 = mlb[2][0][lo5], lj2 = mlb[2][1][lo5];
        const float ms = fmaxf(fmaxf(m, mj0), fmaxf(mj1, mj2));
        const float w0 = exp2f(m - ms), w1 = exp2f(mj0 - ms);
        const float w2 = exp2f(mj1 - ms), w3 = exp2f(mj2 - ms);
        const float linv = 1.f / (l * w0 + lj0 * w1 + lj1 * w2 + lj2 * w3);
        float* orow = out + ((size_t)b * SS + qt * 32 + lo5) * DD;
#pragma unroll
        for (int dt = 0; dt < 4; ++dt)
#pragma unroll
            for (int r = 0; r < 16; ++r) {
                const float o = accT[dt][r] * w0 + obuf[0][dt][r][lane] * w1 +
                                obuf[1][dt][r][lane] * w2 + obuf[2][dt][r][lane] * w3;
                const int drow = (r & 3) + 8 * (r >> 2) + 4 * hi;
                orow[dt * 32 + drow] = o * linv;
            }
    }
}

extern "C" void kernel_launch(void* const* d_in, const int* in_sizes, int n_in,
                              void* d_out, int out_size, void* d_ws, size_t ws_size,
                              hipStream_t stream) {
    const float* x = (const float*)d_in[0];
    const float* theta = (const float*)d_in[1];
    float* outp = (float*)d_out;
    u16* G1 = (u16*)d_ws;                       // 4 MB
    u16* G2 = G1 + (size_t)NB * SS * DD;        // +4 MB

    qmeasure_kernel<<<512, 512, 0, stream>>>(x, theta, G1, G2);
    qattn_kernel<<<512, 256, 0, stream>>>(G1, G2, outp);
}